// Round 1
// baseline (148.639 us; speedup 1.0000x reference)
//
#include <hip/hip_runtime.h>

#define NPTS  65536
#define NBC   76
#define NEGF  (-1e30f)

__device__ __forceinline__ float lrelu(float v) { return v >= 0.0f ? v : 0.01f * v; }

// Order-preserving float->uint key (monotone): max over keys == max over floats.
__device__ __forceinline__ unsigned fkey(float f) {
  unsigned u = __float_as_uint(f);
  return (u & 0x80000000u) ? ~u : (u | 0x80000000u);
}
__device__ __forceinline__ float fdec(unsigned k) {
  return (k & 0x80000000u) ? __uint_as_float(k & 0x7fffffffu) : __uint_as_float(~k);
}

// GEMM layer macro: reads z[k][p] tile from zt (stride 68), weights from wt (transposed,
// wt[k*64+j] = w[j][k]), writes lrelu(w@z + b) back into zt in-place (sync-protected).
#define MLP_LAYER(WT, BS)                                                     \
  {                                                                           \
    float s[4][4];                                                            \
    _Pragma("unroll")                                                         \
    for (int a = 0; a < 4; ++a)                                               \
      _Pragma("unroll")                                                       \
      for (int b = 0; b < 4; ++b) s[a][b] = 0.0f;                             \
    _Pragma("unroll 4")                                                       \
    for (int k = 0; k < 64; ++k) {                                            \
      float4 av = *reinterpret_cast<const float4*>(&WT[k * 64 + j0]);         \
      float4 bv = *reinterpret_cast<const float4*>(&zt[k * 68 + p0]);         \
      float aa[4] = {av.x, av.y, av.z, av.w};                                 \
      float bb[4] = {bv.x, bv.y, bv.z, bv.w};                                 \
      _Pragma("unroll")                                                       \
      for (int a = 0; a < 4; ++a)                                             \
        _Pragma("unroll")                                                     \
        for (int b = 0; b < 4; ++b) s[a][b] += aa[a] * bb[b];                 \
    }                                                                         \
    __syncthreads();                                                          \
    _Pragma("unroll")                                                         \
    for (int jj = 0; jj < 4; ++jj) {                                          \
      float bias = BS[j0 + jj];                                               \
      float4 z;                                                               \
      z.x = lrelu(s[jj][0] + bias);                                           \
      z.y = lrelu(s[jj][1] + bias);                                           \
      z.z = lrelu(s[jj][2] + bias);                                           \
      z.w = lrelu(s[jj][3] + bias);                                           \
      *reinterpret_cast<float4*>(&zt[(j0 + jj) * 68 + p0]) = z;               \
    }                                                                         \
    __syncthreads();                                                          \
  }

__global__ __launch_bounds__(256) void k1_fused(
    const int* __restrict__ x, const float* __restrict__ grid,
    const float* __restrict__ w1, const float* __restrict__ b1,
    const float* __restrict__ w2, const float* __restrict__ b2,
    const float* __restrict__ w3, const float* __restrict__ b3,
    unsigned* __restrict__ keys, float* __restrict__ zfeat)
{
  __shared__ __align__(16) float w1s[128];
  __shared__ float b1s[64], b2s[64], b3s[64];
  __shared__ __align__(16) float w2t[4096];
  __shared__ __align__(16) float w3t[4096];
  __shared__ __align__(16) float zt[64 * 68];   // single tile buffer, pad 68 floats/row
  __shared__ unsigned long long mbits[NBC];
  __shared__ float zf1[64], zf2[64];

  const int t = threadIdx.x;

  // --- stage weights (w2/w3 transposed into LDS; read-side transpose keeps LDS writes clean)
  if (t < 128) w1s[t] = w1[t];
  if (t < 64) { b1s[t] = b1[t]; b2s[t] = b2[t]; b3s[t] = b3[t]; }
  for (int idx = t; idx < 4096; idx += 256) {
    int k = idx >> 6, j = idx & 63;
    w2t[idx] = w2[j * 64 + k];   // w2t[k*64+j] = w2[j][k]
    w3t[idx] = w3[j * 64 + k];
  }
  __syncthreads();

  // --- block 0 additionally computes zero_feat = MLP(0,0) into ws
  if (blockIdx.x == 0) {
    if (t < 64) zf1[t] = lrelu(b1s[t]);
    __syncthreads();
    if (t < 64) {
      float a = b2s[t];
      for (int k = 0; k < 64; ++k) a += w2t[k * 64 + t] * zf1[k];
      zf2[t] = lrelu(a);
    }
    __syncthreads();
    if (t < 64) {
      float a = b3s[t];
      for (int k = 0; k < 64; ++k) a += w3t[k * 64 + t] * zf2[k];
      zfeat[t] = lrelu(a);
    }
  }

  // phase-A mapping: thread -> 4x4 (channel j, point p) block of the 64x64 tile
  const int tk = t >> 4, tp = t & 15;
  const int j0 = tk * 4, p0 = tp * 4;
  // phase-B mapping: thread -> channels {kq, kq+16, kq+32, kq+48} x bc group of 5
  // (16-strided channels => LDS column reads hit 8 distinct banks, 2-way = free)
  const int kq = t & 15, bg = t >> 4;
  const int bcbase = bg * 5;

  float acc[5][4];
  #pragma unroll
  for (int ii = 0; ii < 5; ++ii)
    #pragma unroll
    for (int i = 0; i < 4; ++i) acc[ii][i] = NEGF;

  for (int tile = 0; tile < 2; ++tile) {
    const int n0 = blockIdx.x * 128 + tile * 64;

    // ---- layer 1: z1[k][p] into zt
    float4 g0 = *reinterpret_cast<const float4*>(grid + n0 + p0);
    float4 g1 = *reinterpret_cast<const float4*>(grid + NPTS + n0 + p0);
    #pragma unroll
    for (int kk = 0; kk < 4; ++kk) {
      int k = j0 + kk;
      float a0 = w1s[2 * k], a1 = w1s[2 * k + 1], bb = b1s[k];
      float4 z;
      z.x = lrelu(a0 * g0.x + a1 * g1.x + bb);
      z.y = lrelu(a0 * g0.y + a1 * g1.y + bb);
      z.z = lrelu(a0 * g0.z + a1 * g1.z + bb);
      z.w = lrelu(a0 * g0.w + a1 * g1.w + bb);
      *reinterpret_cast<float4*>(&zt[k * 68 + p0]) = z;
    }
    __syncthreads();

    // ---- layers 2 & 3 (in-place ping in zt, read->sync->write->sync)
    MLP_LAYER(w2t, b2s)
    MLP_LAYER(w3t, b3s)
    // zt now holds feats[k][p] for this tile

    // ---- build 64-bit masks per bc via ballot (wave w handles bc = w, w+4, ...)
    {
      const int wv = t >> 6, lane = t & 63;
      for (int bc = wv; bc < NBC; bc += 4) {
        int v = x[(bc << 16) + n0 + lane];
        unsigned long long m = __ballot(v == 1);
        if (lane == 0) mbits[bc] = m;
      }
    }
    __syncthreads();

    // ---- masked max update (registers)
    {
      unsigned mlo[5], mhi[5];
      #pragma unroll
      for (int ii = 0; ii < 5; ++ii) {
        int bc = bcbase + ii;
        unsigned long long m = (bc < NBC) ? mbits[bc] : 0ull;
        mlo[ii] = (unsigned)m;
        mhi[ii] = (unsigned)(m >> 32);
      }
      #pragma unroll 4
      for (int n = 0; n < 32; ++n) {
        float f0 = zt[(kq)      * 68 + n];
        float f1 = zt[(kq + 16) * 68 + n];
        float f2 = zt[(kq + 32) * 68 + n];
        float f3 = zt[(kq + 48) * 68 + n];
        float h0 = zt[(kq)      * 68 + n + 32];
        float h1 = zt[(kq + 16) * 68 + n + 32];
        float h2 = zt[(kq + 32) * 68 + n + 32];
        float h3 = zt[(kq + 48) * 68 + n + 32];
        #pragma unroll
        for (int ii = 0; ii < 5; ++ii) {
          bool bl = (mlo[ii] >> n) & 1u;
          acc[ii][0] = fmaxf(acc[ii][0], bl ? f0 : NEGF);
          acc[ii][1] = fmaxf(acc[ii][1], bl ? f1 : NEGF);
          acc[ii][2] = fmaxf(acc[ii][2], bl ? f2 : NEGF);
          acc[ii][3] = fmaxf(acc[ii][3], bl ? f3 : NEGF);
          bool bh = (mhi[ii] >> n) & 1u;
          acc[ii][0] = fmaxf(acc[ii][0], bh ? h0 : NEGF);
          acc[ii][1] = fmaxf(acc[ii][1], bh ? h1 : NEGF);
          acc[ii][2] = fmaxf(acc[ii][2], bh ? h2 : NEGF);
          acc[ii][3] = fmaxf(acc[ii][3], bh ? h3 : NEGF);
        }
      }
    }
    __syncthreads();
  }

  // ---- fold this block's partial maxes into global keys (skip untouched = NEGF)
  #pragma unroll
  for (int ii = 0; ii < 5; ++ii) {
    int bc = bcbase + ii;
    if (bc < NBC) {
      #pragma unroll
      for (int i = 0; i < 4; ++i) {
        float v = acc[ii][i];
        if (v > -5e29f) atomicMax(&keys[bc * 64 + kq + 16 * i], fkey(v));
      }
    }
  }
}

__global__ __launch_bounds__(256) void k2_fc(
    const unsigned* __restrict__ keys, const float* __restrict__ zfeat,
    const float* __restrict__ fcw, const float* __restrict__ fcb,
    float* __restrict__ out)
{
  __shared__ float flat[4864];   // [b][c*64+k] linear = keys index
  const int t = threadIdx.x;
  for (int idx = t; idx < 4864; idx += 256) {
    unsigned k = keys[idx];
    flat[idx] = (k == 0u) ? zfeat[idx & 63] : fdec(k);  // key 0 => empty mask
  }
  __syncthreads();

  const int wv = t >> 6, lane = t & 63;
  const int o = blockIdx.x * 4 + wv;          // 128 blocks x 4 waves = 512 outputs
  const float* wrow = fcw + o * 1216;
  float fa0 = 0.f, fa1 = 0.f, fa2 = 0.f, fa3 = 0.f;
  #pragma unroll
  for (int i = 0; i < 19; ++i) {
    int jj = i * 64 + lane;
    float wvv = wrow[jj];
    fa0 += wvv * flat[jj];
    fa1 += wvv * flat[1216 + jj];
    fa2 += wvv * flat[2432 + jj];
    fa3 += wvv * flat[3648 + jj];
  }
  #pragma unroll
  for (int off = 32; off > 0; off >>= 1) {
    fa0 += __shfl_xor(fa0, off);
    fa1 += __shfl_xor(fa1, off);
    fa2 += __shfl_xor(fa2, off);
    fa3 += __shfl_xor(fa3, off);
  }
  // butterfly leaves full sum in every lane; lanes 0..17 write the 18 repeats
  const float scale = 0.028676966733820225f;  // 1/sqrt(1216)
  float cb = fcb[o];
  if (lane < 18) {
    out[(0 * 18 + lane) * 512 + o] = fa0 * scale + cb;
    out[(1 * 18 + lane) * 512 + o] = fa1 * scale + cb;
    out[(2 * 18 + lane) * 512 + o] = fa2 * scale + cb;
    out[(3 * 18 + lane) * 512 + o] = fa3 * scale + cb;
  }
}

extern "C" void kernel_launch(void* const* d_in, const int* in_sizes, int n_in,
                              void* d_out, int out_size, void* d_ws, size_t ws_size,
                              hipStream_t stream)
{
  const int*   x    = (const int*)d_in[0];
  const float* grid = (const float*)d_in[1];
  const float* w1   = (const float*)d_in[2];
  const float* b1   = (const float*)d_in[3];
  const float* w2   = (const float*)d_in[4];
  const float* b2   = (const float*)d_in[5];
  const float* w3   = (const float*)d_in[6];
  const float* b3   = (const float*)d_in[7];
  const float* fcw  = (const float*)d_in[8];
  const float* fcb  = (const float*)d_in[9];
  float* out = (float*)d_out;

  unsigned* keys = (unsigned*)d_ws;           // 4864 uint32 max-keys
  float* zfeat   = (float*)d_ws + 4864;       // 64 floats zero_feat

  hipMemsetAsync(d_ws, 0, 4864 * sizeof(unsigned), stream);  // key 0 == "empty"
  hipLaunchKernelGGL(k1_fused, dim3(512), dim3(256), 0, stream,
                     x, grid, w1, b1, w2, b2, w3, b3, keys, zfeat);
  hipLaunchKernelGGL(k2_fc, dim3(128), dim3(256), 0, stream,
                     keys, zfeat, fcw, fcb, out);
}

// Round 2
// 145.695 us; speedup vs baseline: 1.0202x; 1.0202x over previous
//
#include <hip/hip_runtime.h>

#define NPTS  65536
#define NBC   76
#define NREP  8
#define KEYN  4864   // 76*64

__device__ __forceinline__ float lrelu(float v) { return v >= 0.0f ? v : 0.01f * v; }

// Order-preserving float->uint key: max over keys == max over floats. Key 0 is
// unreachable for finite feats (requires NaN pattern) => 0 doubles as "empty".
__device__ __forceinline__ unsigned fkey(float f) {
  unsigned u = __float_as_uint(f);
  return (u & 0x80000000u) ? ~u : (u | 0x80000000u);
}
__device__ __forceinline__ float fdec(unsigned k) {
  return (k & 0x80000000u) ? __uint_as_float(k & 0x7fffffffu) : __uint_as_float(~k);
}

__global__ __launch_bounds__(256) void k1_fused(
    const int* __restrict__ x, const float* __restrict__ grid,
    const float* __restrict__ w1, const float* __restrict__ b1,
    const float* __restrict__ w2, const float* __restrict__ b2,
    const float* __restrict__ w3, const float* __restrict__ b3,
    unsigned* __restrict__ keys)
{
  // zt[ch][pt]: fp32 bits during MLP, fkey uints after epilogue. stride 68:
  // GEMM reads/writes are lane-consecutive (conflict-free); phase-B b128 reads
  // land 2 addresses/bank-quad (2-way = free per m136).
  __shared__ unsigned zt[64 * 68];
  __shared__ unsigned long long mbits[NBC];

  const int t    = threadIdx.x;
  const int lane = t & 63;
  const int wv   = t >> 6;
  const int n0   = blockIdx.x * 64;

  // ---- masks first: x loads are the longest-latency ops, issue them early.
  // wave wv handles bc = wv*19 .. wv*19+18 (4*19 = 76 exactly)
  {
    int bc0 = wv * 19;
    #pragma unroll
    for (int i = 0; i < 19; ++i) {
      int bc = bc0 + i;
      int v = x[(bc << 16) + n0 + lane];
      unsigned long long m = __ballot(v == 1);
      if (lane == 0) mbits[bc] = m;
    }
  }

  // ---- MLP: wave owns 16 channels (jb..jb+15), lane = point.
  // Weights are wave-uniform -> scalar (s_load) path; force with readfirstlane.
  const int jb = __builtin_amdgcn_readfirstlane(wv * 16);

  // layer 1
  {
    float g0 = grid[n0 + lane];
    float g1 = grid[NPTS + n0 + lane];
    #pragma unroll
    for (int jj = 0; jj < 16; ++jj) {
      int j = jb + jj;
      float z = lrelu(w1[2 * j] * g0 + w1[2 * j + 1] * g1 + b1[j]);
      zt[j * 68 + lane] = __float_as_uint(z);
    }
  }
  __syncthreads();

  float acc[16];

  // layer 2: acc[jj] = b2 + sum_k w2[j][k] * z1[k][lane]
  #pragma unroll
  for (int jj = 0; jj < 16; ++jj) acc[jj] = b2[jb + jj];
  #pragma unroll 4
  for (int k = 0; k < 64; ++k) {
    float zv = __uint_as_float(zt[k * 68 + lane]);
    #pragma unroll
    for (int jj = 0; jj < 16; ++jj) acc[jj] += w2[(jb + jj) * 64 + k] * zv;
  }
  __syncthreads();   // all reads of z1 done
  #pragma unroll
  for (int jj = 0; jj < 16; ++jj)
    zt[(jb + jj) * 68 + lane] = __float_as_uint(lrelu(acc[jj]));
  __syncthreads();

  // layer 3 + fkey epilogue
  #pragma unroll
  for (int jj = 0; jj < 16; ++jj) acc[jj] = b3[jb + jj];
  #pragma unroll 4
  for (int k = 0; k < 64; ++k) {
    float zv = __uint_as_float(zt[k * 68 + lane]);
    #pragma unroll
    for (int jj = 0; jj < 16; ++jj) acc[jj] += w3[(jb + jj) * 64 + k] * zv;
  }
  __syncthreads();
  #pragma unroll
  for (int jj = 0; jj < 16; ++jj)
    zt[(jb + jj) * 68 + lane] = fkey(lrelu(acc[jj]));
  __syncthreads();

  // ---- phase B: masked max in key space.
  // thread -> channels {kq, kq+16, kq+32, kq+48} x 5 bc (bg*5..bg*5+4)
  const int kq = t & 15, bg = t >> 4;
  const int bcbase = bg * 5;

  unsigned mlo[5], mhi[5];
  #pragma unroll
  for (int ii = 0; ii < 5; ++ii) {
    int bc = bcbase + ii;
    unsigned long long m = (bc < NBC) ? mbits[bc] : 0ull;
    mlo[ii] = (unsigned)m;
    mhi[ii] = (unsigned)(m >> 32);
  }

  unsigned uacc[5][4];
  #pragma unroll
  for (int ii = 0; ii < 5; ++ii)
    #pragma unroll
    for (int i = 0; i < 4; ++i) uacc[ii][i] = 0u;

  #pragma unroll 2
  for (int np = 0; np < 8; ++np) {
    const int n = np * 4;
    uint4 lo[4], hi[4];
    #pragma unroll
    for (int i = 0; i < 4; ++i) {
      lo[i] = *reinterpret_cast<const uint4*>(&zt[(kq + 16 * i) * 68 + n]);
      hi[i] = *reinterpret_cast<const uint4*>(&zt[(kq + 16 * i) * 68 + n + 32]);
    }
    #pragma unroll
    for (int ii = 0; ii < 5; ++ii) {
      // sign-extended mask bits (v_bfe_i32): 0 or 0xFFFFFFFF
      unsigned sl0 = (unsigned)((int)(mlo[ii] << (31 - n)) >> 31);
      unsigned sl1 = (unsigned)((int)(mlo[ii] << (30 - n)) >> 31);
      unsigned sl2 = (unsigned)((int)(mlo[ii] << (29 - n)) >> 31);
      unsigned sl3 = (unsigned)((int)(mlo[ii] << (28 - n)) >> 31);
      unsigned sh0 = (unsigned)((int)(mhi[ii] << (31 - n)) >> 31);
      unsigned sh1 = (unsigned)((int)(mhi[ii] << (30 - n)) >> 31);
      unsigned sh2 = (unsigned)((int)(mhi[ii] << (29 - n)) >> 31);
      unsigned sh3 = (unsigned)((int)(mhi[ii] << (28 - n)) >> 31);
      #pragma unroll
      for (int i = 0; i < 4; ++i) {
        unsigned a = uacc[ii][i];
        // max(max(a,b),c) chains -> v_max3_u32
        a = max(max(a, lo[i].x & sl0), lo[i].y & sl1);
        a = max(max(a, lo[i].z & sl2), lo[i].w & sl3);
        a = max(max(a, hi[i].x & sh0), hi[i].y & sh1);
        a = max(max(a, hi[i].z & sh2), hi[i].w & sh3);
        uacc[ii][i] = a;
      }
    }
  }

  // ---- fold into one of 8 key replicas (contention /8)
  unsigned* krep = keys + (blockIdx.x & (NREP - 1)) * KEYN;
  #pragma unroll
  for (int ii = 0; ii < 5; ++ii) {
    int bc = bcbase + ii;
    if (bc < NBC) {
      #pragma unroll
      for (int i = 0; i < 4; ++i) {
        unsigned v = uacc[ii][i];
        if (v) atomicMax(&krep[bc * 64 + kq + 16 * i], v);
      }
    }
  }
}

__global__ __launch_bounds__(256) void k2_fc(
    const unsigned* __restrict__ keys,
    const float* __restrict__ b1, const float* __restrict__ w2,
    const float* __restrict__ b2, const float* __restrict__ w3,
    const float* __restrict__ b3,
    const float* __restrict__ fcw, const float* __restrict__ fcb,
    float* __restrict__ out)
{
  __shared__ float flat[4864];
  __shared__ float za[64], zb[64], zf[64];
  const int t = threadIdx.x;

  // zero_feat = MLP(0,0): tiny, recomputed per block (removes kA dependency)
  if (t < 64) za[t] = lrelu(b1[t]);
  __syncthreads();
  if (t < 64) {
    float s = b2[t];
    #pragma unroll 8
    for (int k = 0; k < 64; ++k) s += w2[t * 64 + k] * za[k];
    zb[t] = lrelu(s);
  }
  __syncthreads();
  if (t < 64) {
    float s = b3[t];
    #pragma unroll 8
    for (int k = 0; k < 64; ++k) s += w3[t * 64 + k] * zb[k];
    zf[t] = lrelu(s);
  }
  __syncthreads();

  // fold 8 replicas + decode (key 0 => empty mask => zero_feat)
  for (int idx = t; idx < 4864; idx += 256) {
    unsigned m = keys[idx];
    #pragma unroll
    for (int r = 1; r < NREP; ++r) m = max(m, keys[r * KEYN + idx]);
    flat[idx] = m ? fdec(m) : zf[idx & 63];
  }
  __syncthreads();

  const int wv = t >> 6, lane = t & 63;
  const int o = blockIdx.x * 4 + wv;          // 128 blocks x 4 waves = 512 outputs
  const float* wrow = fcw + o * 1216;
  float fa0 = 0.f, fa1 = 0.f, fa2 = 0.f, fa3 = 0.f;
  #pragma unroll
  for (int i = 0; i < 19; ++i) {
    int jj = i * 64 + lane;
    float wvv = wrow[jj];
    fa0 += wvv * flat[jj];
    fa1 += wvv * flat[1216 + jj];
    fa2 += wvv * flat[2432 + jj];
    fa3 += wvv * flat[3648 + jj];
  }
  #pragma unroll
  for (int off = 32; off > 0; off >>= 1) {
    fa0 += __shfl_xor(fa0, off);
    fa1 += __shfl_xor(fa1, off);
    fa2 += __shfl_xor(fa2, off);
    fa3 += __shfl_xor(fa3, off);
  }
  const float scale = 0.028676966733820225f;  // 1/sqrt(1216)
  float cb = fcb[o];
  if (lane < 18) {
    out[(0 * 18 + lane) * 512 + o] = fa0 * scale + cb;
    out[(1 * 18 + lane) * 512 + o] = fa1 * scale + cb;
    out[(2 * 18 + lane) * 512 + o] = fa2 * scale + cb;
    out[(3 * 18 + lane) * 512 + o] = fa3 * scale + cb;
  }
}

extern "C" void kernel_launch(void* const* d_in, const int* in_sizes, int n_in,
                              void* d_out, int out_size, void* d_ws, size_t ws_size,
                              hipStream_t stream)
{
  const int*   x    = (const int*)d_in[0];
  const float* grid = (const float*)d_in[1];
  const float* w1   = (const float*)d_in[2];
  const float* b1   = (const float*)d_in[3];
  const float* w2   = (const float*)d_in[4];
  const float* b2   = (const float*)d_in[5];
  const float* w3   = (const float*)d_in[6];
  const float* b3   = (const float*)d_in[7];
  const float* fcw  = (const float*)d_in[8];
  const float* fcb  = (const float*)d_in[9];
  float* out = (float*)d_out;

  unsigned* keys = (unsigned*)d_ws;   // 8 replicas x 4864 uint32 max-keys

  hipMemsetAsync(d_ws, 0, NREP * KEYN * sizeof(unsigned), stream);
  hipLaunchKernelGGL(k1_fused, dim3(1024), dim3(256), 0, stream,
                     x, grid, w1, b1, w2, b2, w3, b3, keys);
  hipLaunchKernelGGL(k2_fc, dim3(128), dim3(256), 0, stream,
                     keys, b1, w2, b2, w3, b3, fcw, fcb, out);
}

// Round 3
// 142.153 us; speedup vs baseline: 1.0456x; 1.0249x over previous
//
#include <hip/hip_runtime.h>

#define NPTS  65536
#define NBC   76
#define NREP  8
#define KEYN  4864   // 76*64

__device__ __forceinline__ float lrelu(float v) { return fmaxf(v, 0.01f * v); }

// Order-preserving float->uint key: max over keys == max over floats. Key 0 is
// unreachable for finite feats => 0 doubles as "empty".
__device__ __forceinline__ unsigned fkey(float f) {
  unsigned u = __float_as_uint(f);
  return (u & 0x80000000u) ? ~u : (u | 0x80000000u);
}
__device__ __forceinline__ float fdec(unsigned k) {
  return (k & 0x80000000u) ? __uint_as_float(k & 0x7fffffffu) : __uint_as_float(~k);
}

__global__ __launch_bounds__(512, 8) void k1_fused(
    const int* __restrict__ x, const float* __restrict__ grid,
    const float* __restrict__ w1, const float* __restrict__ b1,
    const float* __restrict__ w2, const float* __restrict__ b2,
    const float* __restrict__ w3, const float* __restrict__ b3,
    unsigned* __restrict__ keys)
{
  // ping-pong buffers: layer1->zt1, layer2: zt1->zt2, layer3: zt2->zt1(keys).
  // stride 68 floats: GEMM accesses lane-consecutive; phase-B b128 reads 2-way.
  __shared__ unsigned zt1[64 * 68];
  __shared__ unsigned zt2[64 * 68];
  __shared__ unsigned long long mbits[NBC];

  const int t    = threadIdx.x;
  const int lane = t & 63;
  const int wv   = t >> 6;          // 0..7
  const int n0   = blockIdx.x * 64;

  // ---- masks first: longest-latency loads, issue early. wave wv -> bc = wv+8i
  #pragma unroll
  for (int i = 0; i < 10; ++i) {
    int bc = wv + 8 * i;
    if (bc < NBC) {
      int v = x[(bc << 16) + n0 + lane];
      unsigned long long m = __ballot(v == 1);
      if (lane == 0) mbits[bc] = m;
    }
  }

  // ---- MLP: wave owns 8 channels (jb..jb+7), lane = point. Weights wave-uniform.
  const int jb = __builtin_amdgcn_readfirstlane(wv * 8);

  {
    float g0 = grid[n0 + lane];
    float g1 = grid[NPTS + n0 + lane];
    #pragma unroll
    for (int jj = 0; jj < 8; ++jj) {
      int j = jb + jj;
      float z = lrelu(w1[2 * j] * g0 + w1[2 * j + 1] * g1 + b1[j]);
      zt1[j * 68 + lane] = __float_as_uint(z);
    }
  }
  __syncthreads();

  float acc[8];

  // layer 2: zt1 -> zt2
  #pragma unroll
  for (int jj = 0; jj < 8; ++jj) acc[jj] = b2[jb + jj];
  #pragma unroll 4
  for (int k = 0; k < 64; ++k) {
    float zv = __uint_as_float(zt1[k * 68 + lane]);
    #pragma unroll
    for (int jj = 0; jj < 8; ++jj) acc[jj] += w2[(jb + jj) * 64 + k] * zv;
  }
  #pragma unroll
  for (int jj = 0; jj < 8; ++jj)
    zt2[(jb + jj) * 68 + lane] = __float_as_uint(lrelu(acc[jj]));
  __syncthreads();

  // layer 3: zt2 -> zt1 (as monotone keys)
  #pragma unroll
  for (int jj = 0; jj < 8; ++jj) acc[jj] = b3[jb + jj];
  #pragma unroll 4
  for (int k = 0; k < 64; ++k) {
    float zv = __uint_as_float(zt2[k * 68 + lane]);
    #pragma unroll
    for (int jj = 0; jj < 8; ++jj) acc[jj] += w3[(jb + jj) * 64 + k] * zv;
  }
  #pragma unroll
  for (int jj = 0; jj < 8; ++jj)
    zt1[(jb + jj) * 68 + lane] = fkey(lrelu(acc[jj]));
  __syncthreads();   // also covers mbits visibility

  // ---- phase B: masked max in key space.
  // thread -> ch pair {kq, kq+32} x 5 bc; 16 threads share each kq (redundancy 16)
  const int kq = t & 31, bg = t >> 5;
  const int bcbase = bg * 5;

  unsigned mlo[5], mhi[5];
  #pragma unroll
  for (int ii = 0; ii < 5; ++ii) {
    int bc = bcbase + ii;
    unsigned long long m = (bc < NBC) ? mbits[bc] : 0ull;
    mlo[ii] = (unsigned)m;
    mhi[ii] = (unsigned)(m >> 32);
  }

  unsigned uacc[5][2];
  #pragma unroll
  for (int ii = 0; ii < 5; ++ii) { uacc[ii][0] = 0u; uacc[ii][1] = 0u; }

  #pragma unroll 2
  for (int np = 0; np < 8; ++np) {
    const int n = np * 4;
    uint4 lo0 = *reinterpret_cast<const uint4*>(&zt1[kq * 68 + n]);
    uint4 lo1 = *reinterpret_cast<const uint4*>(&zt1[(kq + 32) * 68 + n]);
    uint4 hi0 = *reinterpret_cast<const uint4*>(&zt1[kq * 68 + n + 32]);
    uint4 hi1 = *reinterpret_cast<const uint4*>(&zt1[(kq + 32) * 68 + n + 32]);
    #pragma unroll
    for (int ii = 0; ii < 5; ++ii) {
      unsigned sl0 = (unsigned)((int)(mlo[ii] << (31 - n)) >> 31);
      unsigned sl1 = (unsigned)((int)(mlo[ii] << (30 - n)) >> 31);
      unsigned sl2 = (unsigned)((int)(mlo[ii] << (29 - n)) >> 31);
      unsigned sl3 = (unsigned)((int)(mlo[ii] << (28 - n)) >> 31);
      unsigned sh0 = (unsigned)((int)(mhi[ii] << (31 - n)) >> 31);
      unsigned sh1 = (unsigned)((int)(mhi[ii] << (30 - n)) >> 31);
      unsigned sh2 = (unsigned)((int)(mhi[ii] << (29 - n)) >> 31);
      unsigned sh3 = (unsigned)((int)(mhi[ii] << (28 - n)) >> 31);
      unsigned a0 = uacc[ii][0], a1 = uacc[ii][1];
      a0 = max(max(a0, lo0.x & sl0), lo0.y & sl1);
      a0 = max(max(a0, lo0.z & sl2), lo0.w & sl3);
      a0 = max(max(a0, hi0.x & sh0), hi0.y & sh1);
      a0 = max(max(a0, hi0.z & sh2), hi0.w & sh3);
      a1 = max(max(a1, lo1.x & sl0), lo1.y & sl1);
      a1 = max(max(a1, lo1.z & sl2), lo1.w & sl3);
      a1 = max(max(a1, hi1.x & sh0), hi1.y & sh1);
      a1 = max(max(a1, hi1.z & sh2), hi1.w & sh3);
      uacc[ii][0] = a0; uacc[ii][1] = a1;
    }
  }

  // ---- fold into one of 8 key replicas (contention /8)
  unsigned* krep = keys + (blockIdx.x & (NREP - 1)) * KEYN;
  #pragma unroll
  for (int ii = 0; ii < 5; ++ii) {
    int bc = bcbase + ii;
    if (bc < NBC) {
      unsigned v0 = uacc[ii][0], v1 = uacc[ii][1];
      if (v0) atomicMax(&krep[bc * 64 + kq], v0);
      if (v1) atomicMax(&krep[bc * 64 + kq + 32], v1);
    }
  }
}

__global__ __launch_bounds__(256) void k2_fc(
    const unsigned* __restrict__ keys,
    const float* __restrict__ b1, const float* __restrict__ w2,
    const float* __restrict__ b2, const float* __restrict__ w3,
    const float* __restrict__ b3,
    const float* __restrict__ fcw, const float* __restrict__ fcb,
    float* __restrict__ out)
{
  __shared__ float flat[4864];
  __shared__ float za[64], zb[64], zf[64];
  const int t = threadIdx.x;

  // zero_feat = MLP(0,0): tiny, recomputed per block
  if (t < 64) za[t] = lrelu(b1[t]);
  __syncthreads();
  if (t < 64) {
    float s = b2[t];
    #pragma unroll 8
    for (int k = 0; k < 64; ++k) s += w2[t * 64 + k] * za[k];
    zb[t] = lrelu(s);
  }
  __syncthreads();
  if (t < 64) {
    float s = b3[t];
    #pragma unroll 8
    for (int k = 0; k < 64; ++k) s += w3[t * 64 + k] * zb[k];
    zf[t] = lrelu(s);
  }
  __syncthreads();

  // fold 8 replicas + decode (key 0 => empty mask => zero_feat)
  for (int idx = t; idx < 4864; idx += 256) {
    unsigned m = keys[idx];
    #pragma unroll
    for (int r = 1; r < NREP; ++r) m = max(m, keys[r * KEYN + idx]);
    flat[idx] = m ? fdec(m) : zf[idx & 63];
  }
  __syncthreads();

  const int wv = t >> 6, lane = t & 63;
  const int o = blockIdx.x * 4 + wv;          // 128 blocks x 4 waves = 512 outputs
  const float* wrow = fcw + o * 1216;
  float fa0 = 0.f, fa1 = 0.f, fa2 = 0.f, fa3 = 0.f;
  #pragma unroll
  for (int i = 0; i < 19; ++i) {
    int jj = i * 64 + lane;
    float wvv = wrow[jj];
    fa0 += wvv * flat[jj];
    fa1 += wvv * flat[1216 + jj];
    fa2 += wvv * flat[2432 + jj];
    fa3 += wvv * flat[3648 + jj];
  }
  #pragma unroll
  for (int off = 32; off > 0; off >>= 1) {
    fa0 += __shfl_xor(fa0, off);
    fa1 += __shfl_xor(fa1, off);
    fa2 += __shfl_xor(fa2, off);
    fa3 += __shfl_xor(fa3, off);
  }
  const float scale = 0.028676966733820225f;  // 1/sqrt(1216)
  float cb = fcb[o];
  if (lane < 18) {
    out[(0 * 18 + lane) * 512 + o] = fa0 * scale + cb;
    out[(1 * 18 + lane) * 512 + o] = fa1 * scale + cb;
    out[(2 * 18 + lane) * 512 + o] = fa2 * scale + cb;
    out[(3 * 18 + lane) * 512 + o] = fa3 * scale + cb;
  }
}

extern "C" void kernel_launch(void* const* d_in, const int* in_sizes, int n_in,
                              void* d_out, int out_size, void* d_ws, size_t ws_size,
                              hipStream_t stream)
{
  const int*   x    = (const int*)d_in[0];
  const float* grid = (const float*)d_in[1];
  const float* w1   = (const float*)d_in[2];
  const float* b1   = (const float*)d_in[3];
  const float* w2   = (const float*)d_in[4];
  const float* b2   = (const float*)d_in[5];
  const float* w3   = (const float*)d_in[6];
  const float* b3   = (const float*)d_in[7];
  const float* fcw  = (const float*)d_in[8];
  const float* fcb  = (const float*)d_in[9];
  float* out = (float*)d_out;

  unsigned* keys = (unsigned*)d_ws;   // 8 replicas x 4864 uint32 max-keys

  hipMemsetAsync(d_ws, 0, NREP * KEYN * sizeof(unsigned), stream);
  hipLaunchKernelGGL(k1_fused, dim3(1024), dim3(512), 0, stream,
                     x, grid, w1, b1, w2, b2, w3, b3, keys);
  hipLaunchKernelGGL(k2_fc, dim3(128), dim3(256), 0, stream,
                     keys, b1, w2, b2, w3, b3, fcw, fcb, out);
}

// Round 5
// 129.805 us; speedup vs baseline: 1.1451x; 1.0951x over previous
//
#include <hip/hip_runtime.h>

#define NPTS  65536
#define NBC   76
#define NREP  8
#define KEYN  4864   // 76*64

typedef _Float16 f16;
typedef __fp16   h16x2 __attribute__((ext_vector_type(2)));   // cvt_pkrtz native type
typedef _Float16 f16x8 __attribute__((ext_vector_type(8)));
typedef float    f32x4 __attribute__((ext_vector_type(4)));

__device__ __forceinline__ float lrelu(float v) { return fmaxf(v, 0.01f * v); }

// two f32 -> packed f16 bits (RTZ; monotone, so max commutes with quantization)
__device__ __forceinline__ unsigned pkrtz(float lo, float hi) {
  h16x2 p = __builtin_amdgcn_cvt_pkrtz(lo, hi);
  return __builtin_bit_cast(unsigned, p);
}
// packed f16 bits -> packed order-preserving u16 keys (both halves).
// key 0 requires f16 NaN pattern => 0 doubles as "empty" sentinel.
__device__ __forceinline__ unsigned pkey(unsigned u) {
  unsigned t = (u >> 15) & 0x00010001u;
  return u ^ (0x80008000u | (t * 0x7FFFu));
}
__device__ __forceinline__ unsigned pkmax(unsigned a, unsigned b) {
  unsigned d;
  asm("v_pk_max_u16 %0, %1, %2" : "=v"(d) : "v"(a), "v"(b));
  return d;
}
// sign-extend bit b of x to all 32 bits (1 VALU op via v_bfe_i32)
__device__ __forceinline__ unsigned sext1(unsigned x, int b) {
  return (unsigned)(((int)(x << (31 - b))) >> 31);
}

__global__ __launch_bounds__(512, 8) void k1_fused(
    const int* __restrict__ x, const float* __restrict__ grid,
    const float* __restrict__ w1, const float* __restrict__ b1,
    const float* __restrict__ w2, const float* __restrict__ b2,
    const float* __restrict__ w3, const float* __restrict__ b3,
    unsigned* __restrict__ keys)
{
  // LDS plan (37.5 KB -> 4 blocks/CU, 8 waves/SIMD):
  //   zA  [64pt][72k] f16  (9216 B)   layer1 out / layer2 B-operand
  //   zB  [64pt][72k] f16  (9216 B)   layer2 out / layer3 B-operand
  //   wf2 [64ch][72k] f16  (9216 B)   layer2 A-operand; DEAD after layer2
  //   wf3 [64ch][72k] f16  (9216 B)   layer3 A-operand
  //   zkey[32row][68] u32  (8704 B)   aliases wf2 (written in layer3 epilogue)
  // pad-to-72 rows: b128 row reads start at bank 36*r mod 32 -> <=2-way (free)
  __shared__ __align__(16) unsigned char smem[36864];
  __shared__ unsigned long long mbits[NBC];
  f16* zA  = (f16*)(smem);
  f16* zB  = (f16*)(smem + 9216);
  f16* wf2 = (f16*)(smem + 18432);
  f16* wf3 = (f16*)(smem + 27648);
  unsigned* zkey = (unsigned*)(smem + 18432);   // alias wf2

  const int t    = threadIdx.x;
  const int lane = t & 63;
  const int wv   = t >> 6;          // 0..7
  const int n0   = blockIdx.x * 64;

  // ---- x loads first (longest latency); ballots deferred past the MFMAs.
  int xv[10];
  #pragma unroll
  for (int i = 0; i < 10; ++i) {
    int bc = wv + 8 * i;                       // wave-uniform
    xv[i] = (bc < NBC) ? x[(bc << 16) + n0 + lane] : 0;
  }

  // ---- stage w2/w3 as f16 rows [ch][k] (coalesced 32B/thread)
  {
    int ch = t >> 3, k0 = (t & 7) * 8;
    const float4* s2 = (const float4*)(w2 + ch * 64 + k0);
    float4 a = s2[0], b = s2[1];
    *(uint4*)&wf2[ch * 72 + k0] =
        make_uint4(pkrtz(a.x, a.y), pkrtz(a.z, a.w), pkrtz(b.x, b.y), pkrtz(b.z, b.w));
    const float4* s3 = (const float4*)(w3 + ch * 64 + k0);
    float4 c = s3[0], d = s3[1];
    *(uint4*)&wf3[ch * 72 + k0] =
        make_uint4(pkrtz(c.x, c.y), pkrtz(c.z, c.w), pkrtz(d.x, d.y), pkrtz(d.z, d.w));
  }

  // ---- layer 1: wave wv -> channels wv*8..wv*8+7, pt = lane. Writes zA[pt][k].
  {
    float g0 = grid[n0 + lane], g1 = grid[NPTS + n0 + lane];
    unsigned uo[4];
    #pragma unroll
    for (int p = 0; p < 4; ++p) {
      int j = wv * 8 + p * 2;
      float z0 = lrelu(w1[2 * j] * g0 + w1[2 * j + 1] * g1 + b1[j]);
      float z1 = lrelu(w1[2 * j + 2] * g0 + w1[2 * j + 3] * g1 + b1[j + 1]);
      uo[p] = pkrtz(z0, z1);
    }
    *(uint4*)&zA[lane * 72 + wv * 8] = make_uint4(uo[0], uo[1], uo[2], uo[3]);
  }
  __syncthreads();

  // ---- MFMA tiling: wave -> 16ch x 32pt; both operands read as [row][k]
  // (gemm_bt convention: D[m][n] = sum_k A[m][k]*B[n][k]).
  const int chb = (wv & 3) * 16, pth = (wv >> 2) * 32;
  const int c15 = lane & 15, q = lane >> 4;
  const int chq = chb + q * 4;                 // 4 consecutive ch in C/D regs
  const int pt0 = pth + c15, pt1 = pth + 16 + c15;

  f32x4 acc0, acc1;

  // ---- layer 2 (A=wf2, B=zA) -> zB[pt][ch]
  {
    float4 bias = *(const float4*)(b2 + chq);  // C-init with bias
    acc0 = (f32x4){bias.x, bias.y, bias.z, bias.w};
    acc1 = acc0;
    #pragma unroll
    for (int k0 = 0; k0 < 64; k0 += 32) {
      f16x8 af = *(const f16x8*)&wf2[(chb + c15) * 72 + k0 + q * 8];
      f16x8 b0 = *(const f16x8*)&zA[pt0 * 72 + k0 + q * 8];
      f16x8 b1f = *(const f16x8*)&zA[pt1 * 72 + k0 + q * 8];
      acc0 = __builtin_amdgcn_mfma_f32_16x16x32_f16(af, b0, acc0, 0, 0, 0);
      acc1 = __builtin_amdgcn_mfma_f32_16x16x32_f16(af, b1f, acc1, 0, 0, 0);
    }
    // C/D: col=lane&15 (pt), row=q*4+reg (ch) -> 4 consecutive ch per lane
    *(uint2*)&zB[pt0 * 72 + chq] =
        make_uint2(pkrtz(lrelu(acc0[0]), lrelu(acc0[1])),
                   pkrtz(lrelu(acc0[2]), lrelu(acc0[3])));
    *(uint2*)&zB[pt1 * 72 + chq] =
        make_uint2(pkrtz(lrelu(acc1[0]), lrelu(acc1[1])),
                   pkrtz(lrelu(acc1[2]), lrelu(acc1[3])));
  }

  // ---- ballots now (x long since arrived; hides nothing critical)
  #pragma unroll
  for (int i = 0; i < 10; ++i) {
    int bc = wv + 8 * i;
    unsigned long long m = __ballot(xv[i] == 1);
    if (bc < NBC && lane == 0) mbits[bc] = m;
  }
  __syncthreads();   // zB ready; wf2 dead from here

  // ---- layer 3 (A=wf3, B=zB) -> packed keys into zkey[ch>>1][pt] (alias wf2)
  {
    float4 bias = *(const float4*)(b3 + chq);
    acc0 = (f32x4){bias.x, bias.y, bias.z, bias.w};
    acc1 = acc0;
    #pragma unroll
    for (int k0 = 0; k0 < 64; k0 += 32) {
      f16x8 af = *(const f16x8*)&wf3[(chb + c15) * 72 + k0 + q * 8];
      f16x8 b0 = *(const f16x8*)&zB[pt0 * 72 + k0 + q * 8];
      f16x8 b1f = *(const f16x8*)&zB[pt1 * 72 + k0 + q * 8];
      acc0 = __builtin_amdgcn_mfma_f32_16x16x32_f16(af, b0, acc0, 0, 0, 0);
      acc1 = __builtin_amdgcn_mfma_f32_16x16x32_f16(af, b1f, acc1, 0, 0, 0);
    }
    int r0 = chq >> 1;   // rows pack ch pairs (2r, 2r+1); chq is even
    zkey[r0 * 68 + pt0]       = pkey(pkrtz(lrelu(acc0[0]), lrelu(acc0[1])));
    zkey[(r0 + 1) * 68 + pt0] = pkey(pkrtz(lrelu(acc0[2]), lrelu(acc0[3])));
    zkey[r0 * 68 + pt1]       = pkey(pkrtz(lrelu(acc1[0]), lrelu(acc1[1])));
    zkey[(r0 + 1) * 68 + pt1] = pkey(pkrtz(lrelu(acc1[2]), lrelu(acc1[3])));
  }
  __syncthreads();

  // ---- phase B: masked max in packed-u16 key space.
  // thread -> row rw (ch pair) x 5 bc; 512 = 32 rows x 16 bc-groups, no overlap
  const int rw = t & 31, bg = t >> 5;
  const int bc0 = bg * 5;

  unsigned mlo[5], mhi[5], uacc[5];
  #pragma unroll
  for (int ii = 0; ii < 5; ++ii) {
    int bc = bc0 + ii;
    unsigned long long m = (bc < NBC) ? mbits[bc] : 0ull;
    mlo[ii] = (unsigned)m;
    mhi[ii] = (unsigned)(m >> 32);
    uacc[ii] = 0u;
  }

  #pragma unroll
  for (int np = 0; np < 16; ++np) {
    uint4 z4 = *(const uint4*)&zkey[rw * 68 + np * 4];
    const int p = np * 4, pb = p & 31;
    #pragma unroll
    for (int ii = 0; ii < 5; ++ii) {
      unsigned m = (p < 32) ? mlo[ii] : mhi[ii];
      unsigned s0 = sext1(m, pb),     s1 = sext1(m, pb + 1);
      unsigned s2 = sext1(m, pb + 2), s3 = sext1(m, pb + 3);
      unsigned a = uacc[ii];
      a = pkmax(a, z4.x & s0); a = pkmax(a, z4.y & s1);
      a = pkmax(a, z4.z & s2); a = pkmax(a, z4.w & s3);
      uacc[ii] = a;
    }
  }

  // ---- fold into one of 8 key replicas (u16 keys zero-extended into u32 slots)
  unsigned* krep = keys + (blockIdx.x & (NREP - 1)) * KEYN;
  #pragma unroll
  for (int ii = 0; ii < 5; ++ii) {
    int bc = bc0 + ii;
    if (bc < NBC) {
      unsigned lo = uacc[ii] & 0xFFFFu, hi = uacc[ii] >> 16;
      if (lo) atomicMax(&krep[bc * 64 + 2 * rw], lo);
      if (hi) atomicMax(&krep[bc * 64 + 2 * rw + 1], hi);
    }
  }
}

__global__ __launch_bounds__(256) void k2_fc(
    const unsigned* __restrict__ keys,
    const float* __restrict__ b1, const float* __restrict__ w2,
    const float* __restrict__ b2, const float* __restrict__ w3,
    const float* __restrict__ b3,
    const float* __restrict__ fcw, const float* __restrict__ fcb,
    float* __restrict__ out)
{
  __shared__ float flat[4864];
  __shared__ float za[64], zb[64], zf[64];
  const int t = threadIdx.x;

  // zero_feat = fp32 MLP(0,0): tiny, recomputed per block
  if (t < 64) za[t] = lrelu(b1[t]);
  __syncthreads();
  if (t < 64) {
    float s = b2[t];
    #pragma unroll 8
    for (int k = 0; k < 64; ++k) s += w2[t * 64 + k] * za[k];
    zb[t] = lrelu(s);
  }
  __syncthreads();
  if (t < 64) {
    float s = b3[t];
    #pragma unroll 8
    for (int k = 0; k < 64; ++k) s += w3[t * 64 + k] * zb[k];
    zf[t] = lrelu(s);
  }
  __syncthreads();

  // fold 8 replicas + decode u16 key -> f16 -> f32 (key 0 => empty => zero_feat)
  for (int idx = t; idx < 4864; idx += 256) {
    unsigned m = keys[idx];
    #pragma unroll
    for (int r = 1; r < NREP; ++r) m = max(m, keys[r * KEYN + idx]);
    float v;
    if (m) {
      unsigned u = (m & 0x8000u) ? (m ^ 0x8000u) : (~m & 0xFFFFu);
      unsigned short us = (unsigned short)u;
      v = (float)__builtin_bit_cast(f16, us);
    } else {
      v = zf[idx & 63];
    }
    flat[idx] = v;
  }
  __syncthreads();

  const int wv = t >> 6, lane = t & 63;
  const int o = blockIdx.x * 4 + wv;          // 128 blocks x 4 waves = 512 outputs
  const float* wrow = fcw + o * 1216;
  float fa0 = 0.f, fa1 = 0.f, fa2 = 0.f, fa3 = 0.f;
  #pragma unroll
  for (int i = 0; i < 19; ++i) {
    int jj = i * 64 + lane;
    float wvv = wrow[jj];
    fa0 += wvv * flat[jj];
    fa1 += wvv * flat[1216 + jj];
    fa2 += wvv * flat[2432 + jj];
    fa3 += wvv * flat[3648 + jj];
  }
  #pragma unroll
  for (int off = 32; off > 0; off >>= 1) {
    fa0 += __shfl_xor(fa0, off);
    fa1 += __shfl_xor(fa1, off);
    fa2 += __shfl_xor(fa2, off);
    fa3 += __shfl_xor(fa3, off);
  }
  const float scale = 0.028676966733820225f;  // 1/sqrt(1216)
  float cb = fcb[o];
  if (lane < 18) {
    out[(0 * 18 + lane) * 512 + o] = fa0 * scale + cb;
    out[(1 * 18 + lane) * 512 + o] = fa1 * scale + cb;
    out[(2 * 18 + lane) * 512 + o] = fa2 * scale + cb;
    out[(3 * 18 + lane) * 512 + o] = fa3 * scale + cb;
  }
}

extern "C" void kernel_launch(void* const* d_in, const int* in_sizes, int n_in,
                              void* d_out, int out_size, void* d_ws, size_t ws_size,
                              hipStream_t stream)
{
  const int*   x    = (const int*)d_in[0];
  const float* grid = (const float*)d_in[1];
  const float* w1   = (const float*)d_in[2];
  const float* b1   = (const float*)d_in[3];
  const float* w2   = (const float*)d_in[4];
  const float* b2   = (const float*)d_in[5];
  const float* w3   = (const float*)d_in[6];
  const float* b3   = (const float*)d_in[7];
  const float* fcw  = (const float*)d_in[8];
  const float* fcb  = (const float*)d_in[9];
  float* out = (float*)d_out;

  unsigned* keys = (unsigned*)d_ws;   // 8 replicas x 4864 u32 max-keys

  (void)hipMemsetAsync(d_ws, 0, NREP * KEYN * sizeof(unsigned), stream);
  hipLaunchKernelGGL(k1_fused, dim3(1024), dim3(512), 0, stream,
                     x, grid, w1, b1, w2, b2, w3, b3, keys);
  hipLaunchKernelGGL(k2_fc, dim3(128), dim3(256), 0, stream,
                     keys, b1, w2, b2, w3, b3, fcw, fcb, out);
}